// Round 2
// baseline (79.635 us; speedup 1.0000x reference)
//
#include <hip/hip_runtime.h>
#include <math.h>

#define N_GAUSS 2048
#define IMG_H 512
#define IMG_W 512
#define TILE_W 64
#define TILE_H 4
#define TILES_X (IMG_W / TILE_W)   // 8
#define TILES_Y (IMG_H / TILE_H)   // 128
#define N_TILES (TILES_X * TILES_Y) // 1024
#define PCACHE 512                  // param-cache capacity (expected count ~8)

__global__ __launch_bounds__(256) void splat_tiled(
    const float* __restrict__ xyz,
    const float* __restrict__ chol,
    const float* __restrict__ opacity,
    const float* __restrict__ fdc,
    float* __restrict__ out)
{
    __shared__ int   s_count;
    __shared__ int   s_idx[N_GAUSS];      // 8 KB, arrival-order gaussian ids
    __shared__ float s_par[PCACHE][9];    // 18 KB: cx,cy,c0,c1,c2,op,cr,cg,cb

    const int tile = blockIdx.x;
    const int tx = tile % TILES_X;
    const int ty = tile / TILES_X;
    const int t  = threadIdx.x;

    // tile pixel-center bounds
    const float x0 = (float)(tx * TILE_W) + 0.5f;
    const float x1 = (float)(tx * TILE_W + TILE_W - 1) + 0.5f;
    const float y0 = (float)(ty * TILE_H) + 0.5f;
    const float y1 = (float)(ty * TILE_H + TILE_H - 1) + 0.5f;

    if (t == 0) s_count = 0;
    __syncthreads();

    // ---- Stage A: cooperative filter of all gaussians against this tile ----
    for (int g = t; g < N_GAUSS; g += 256) {
        float mx = tanhf(xyz[2 * g]);
        float my = tanhf(xyz[2 * g + 1]);
        float cx = 0.5f * (mx + 1.0f) * (float)IMG_W;
        float cy = 0.5f * (my + 1.0f) * (float)IMG_H;

        float l1 = chol[3 * g]     + 0.5f;   // cholesky_bound = [0.5, 0, 0.5]
        float l2 = chol[3 * g + 1];
        float l3 = chol[3 * g + 2] + 0.5f;
        float s11 = l1 * l1;
        float s22 = l2 * l2 + l3 * l3;

        float op = 1.0f / (1.0f + __expf(-opacity[g]));
        // alpha = op*exp(-sigma) >= 1/255  =>  sigma <= log(255*op)
        float smax = __logf(255.0f * op);
        if (smax <= 0.0f) continue;

        // conservative extent from covariance diagonal (+1 px margin);
        // any over-coverage is rejected by the exact per-pixel test below
        float rx = sqrtf(2.0f * smax * s11) + 1.0f;
        float ry = sqrtf(2.0f * smax * s22) + 1.0f;

        if (cx + rx < x0 || cx - rx > x1 || cy + ry < y0 || cy - ry > y1)
            continue;

        int pos = atomicAdd(&s_count, 1);
        s_idx[pos] = g;
        if (pos < PCACHE) {
            float s12 = l1 * l2;
            float det = s11 * s22 - s12 * s12;
            float inv = 1.0f / det;
            s_par[pos][0] = cx;
            s_par[pos][1] = cy;
            s_par[pos][2] =  s22 * inv;
            s_par[pos][3] = -s12 * inv;
            s_par[pos][4] =  s11 * inv;
            s_par[pos][5] = 1.0f / (1.0f + expf(-opacity[g]));      // precise op
            s_par[pos][6] = 1.0f / (1.0f + expf(-fdc[3 * g]));
            s_par[pos][7] = 1.0f / (1.0f + expf(-fdc[3 * g + 1]));
            s_par[pos][8] = 1.0f / (1.0f + expf(-fdc[3 * g + 2]));
        }
    }
    __syncthreads();

    // ---- Stage B: one thread per pixel, accumulate over survivors ----
    const int w = tx * TILE_W + (t & (TILE_W - 1));
    const int h = ty * TILE_H + (t >> 6);
    const float px = (float)w + 0.5f;
    const float py = (float)h + 0.5f;

    float R = 0.0f, G = 0.0f, B = 0.0f;
    const int cnt = s_count;
    for (int i = 0; i < cnt; i++) {
        float cx, cy, c0, c1, c2, op, cr, cg, cb;
        if (i < PCACHE) {
            cx = s_par[i][0]; cy = s_par[i][1];
            c0 = s_par[i][2]; c1 = s_par[i][3]; c2 = s_par[i][4];
            op = s_par[i][5];
            cr = s_par[i][6]; cg = s_par[i][7]; cb = s_par[i][8];
        } else {
            // overflow path (count > PCACHE) — recompute from raw inputs
            int g = s_idx[i];
            float mx = tanhf(xyz[2 * g]);
            float my = tanhf(xyz[2 * g + 1]);
            cx = 0.5f * (mx + 1.0f) * (float)IMG_W;
            cy = 0.5f * (my + 1.0f) * (float)IMG_H;
            float l1 = chol[3 * g]     + 0.5f;
            float l2 = chol[3 * g + 1];
            float l3 = chol[3 * g + 2] + 0.5f;
            float s11 = l1 * l1;
            float s12 = l1 * l2;
            float s22 = l2 * l2 + l3 * l3;
            float det = s11 * s22 - s12 * s12;
            float inv = 1.0f / det;
            c0 =  s22 * inv; c1 = -s12 * inv; c2 = s11 * inv;
            op = 1.0f / (1.0f + expf(-opacity[g]));
            cr = 1.0f / (1.0f + expf(-fdc[3 * g]));
            cg = 1.0f / (1.0f + expf(-fdc[3 * g + 1]));
            cb = 1.0f / (1.0f + expf(-fdc[3 * g + 2]));
        }
        float dx = cx - px;
        float dy = cy - py;
        // same association order as reference
        float sigma = 0.5f * c0 * dx * dx + 0.5f * c2 * dy * dy + c1 * dy * dx;
        if (sigma < 0.0f) continue;
        float alpha = fminf(op * expf(-sigma), 0.999f);
        if (alpha < (1.0f / 255.0f)) continue;
        R += alpha * cr;
        G += alpha * cg;
        B += alpha * cb;
    }

    const int p = h * IMG_W + w;
    out[p]                     = fminf(fmaxf(R, 0.0f), 1.0f);
    out[IMG_H * IMG_W + p]     = fminf(fmaxf(G, 0.0f), 1.0f);
    out[2 * IMG_H * IMG_W + p] = fminf(fmaxf(B, 0.0f), 1.0f);
}

extern "C" void kernel_launch(void* const* d_in, const int* in_sizes, int n_in,
                              void* d_out, int out_size, void* d_ws, size_t ws_size,
                              hipStream_t stream) {
    const float* xyz     = (const float*)d_in[0];  // (1, N, 2)
    const float* chol    = (const float*)d_in[1];  // (1, N, 3)
    const float* opacity = (const float*)d_in[2];  // (N, 1)
    const float* fdc     = (const float*)d_in[3];  // (N, 3)
    // d_in[4] = frame_index, always 0 (T == 1)

    float* out = (float*)d_out;                    // (1, 3, H, W)

    splat_tiled<<<N_TILES, 256, 0, stream>>>(xyz, chol, opacity, fdc, out);
}

// Round 3
// 75.294 us; speedup vs baseline: 1.0577x; 1.0577x over previous
//
#include <hip/hip_runtime.h>
#include <math.h>

#define N_GAUSS 2048
#define IMG_H 512
#define IMG_W 512
#define TILE_W 64
#define TILE_H 4
#define TILES_X (IMG_W / TILE_W)    // 8
#define TILES_Y (IMG_H / TILE_H)    // 128
#define N_TILES (TILES_X * TILES_Y) // 1024

// ws layout: per gaussian, 4 x float4 (64 B):
//   q0 = (cx, cy, c0, c1)
//   q1 = (c2, op, cr, cg)
//   q2 = (cb, 0, 0, 0)
//   q3 = (bx0, bx1, by0, by1)   bbox in pixel-center coords; empty if bx0 > bx1

__global__ __launch_bounds__(256) void prep_kernel(
    const float* __restrict__ xyz,
    const float* __restrict__ chol,
    const float* __restrict__ opacity,
    const float* __restrict__ fdc,
    float4* __restrict__ ws)
{
    int g = blockIdx.x * 256 + threadIdx.x;
    if (g >= N_GAUSS) return;

    float mx = tanhf(xyz[2 * g]);
    float my = tanhf(xyz[2 * g + 1]);
    float cx = 0.5f * (mx + 1.0f) * (float)IMG_W;
    float cy = 0.5f * (my + 1.0f) * (float)IMG_H;

    float l1 = chol[3 * g]     + 0.5f;   // cholesky_bound = [0.5, 0, 0.5]
    float l2 = chol[3 * g + 1];
    float l3 = chol[3 * g + 2] + 0.5f;
    float s11 = l1 * l1;
    float s12 = l1 * l2;
    float s22 = l2 * l2 + l3 * l3;
    float det = s11 * s22 - s12 * s12;
    float inv = 1.0f / det;
    float c0 =  s22 * inv;
    float c1 = -s12 * inv;
    float c2 =  s11 * inv;

    float op = 1.0f / (1.0f + expf(-opacity[g]));
    float cr = 1.0f / (1.0f + expf(-fdc[3 * g]));
    float cg = 1.0f / (1.0f + expf(-fdc[3 * g + 1]));
    float cb = 1.0f / (1.0f + expf(-fdc[3 * g + 2]));

    // alpha = op*exp(-sigma) >= 1/255  =>  sigma <= log(255*op)
    float smax = logf(255.0f * op);
    float bx0, bx1, by0, by1;
    if (smax <= 0.0f) {
        bx0 = 1.0f; bx1 = 0.0f; by0 = 1.0f; by1 = 0.0f;  // empty bbox
    } else {
        // conservative extent from covariance diagonal (+1 px margin);
        // over-coverage is rejected by the exact per-pixel test in stage B
        float rx = sqrtf(2.0f * smax * s11) + 1.0f;
        float ry = sqrtf(2.0f * smax * s22) + 1.0f;
        bx0 = cx - rx; bx1 = cx + rx;
        by0 = cy - ry; by1 = cy + ry;
    }

    ws[g * 4 + 0] = make_float4(cx, cy, c0, c1);
    ws[g * 4 + 1] = make_float4(c2, op, cr, cg);
    ws[g * 4 + 2] = make_float4(cb, 0.0f, 0.0f, 0.0f);
    ws[g * 4 + 3] = make_float4(bx0, bx1, by0, by1);
}

__global__ __launch_bounds__(256) void splat_tiled(
    const float4* __restrict__ ws,
    float* __restrict__ out)
{
    __shared__ int s_count;
    __shared__ int s_idx[N_GAUSS];   // 8 KB, arrival-order survivor ids

    const int tile = blockIdx.x;
    const int tx = tile % TILES_X;
    const int ty = tile / TILES_X;
    const int t  = threadIdx.x;

    // tile pixel-center bounds
    const float x0 = (float)(tx * TILE_W) + 0.5f;
    const float x1 = (float)(tx * TILE_W + TILE_W - 1) + 0.5f;
    const float y0 = (float)(ty * TILE_H) + 0.5f;
    const float y1 = (float)(ty * TILE_H + TILE_H - 1) + 0.5f;

    if (t == 0) s_count = 0;
    __syncthreads();

    // ---- Stage A: bbox-vs-tile test, 8 gaussians per thread ----
    #pragma unroll
    for (int k = 0; k < N_GAUSS / 256; k++) {
        int g = k * 256 + t;
        float4 bb = ws[g * 4 + 3];   // (bx0, bx1, by0, by1), coalesced stride-64B
        if (bb.x <= x1 && bb.y >= x0 && bb.z <= y1 && bb.w >= y0) {
            int pos = atomicAdd(&s_count, 1);
            s_idx[pos] = g;
        }
    }
    __syncthreads();

    // ---- Stage B: one thread per pixel, accumulate over survivors ----
    const int w = tx * TILE_W + (t & (TILE_W - 1));
    const int h = ty * TILE_H + (t >> 6);
    const float px = (float)w + 0.5f;
    const float py = (float)h + 0.5f;

    float R = 0.0f, G = 0.0f, B = 0.0f;
    const int cnt = s_count;
    for (int i = 0; i < cnt; i++) {
        int g = s_idx[i];
        // wave-uniform addresses -> broadcast loads, L2-hot
        float4 q0 = ws[g * 4 + 0];
        float4 q1 = ws[g * 4 + 1];
        float4 q2 = ws[g * 4 + 2];
        float dx = q0.x - px;
        float dy = q0.y - py;
        // same association order as reference
        float sigma = 0.5f * q0.z * dx * dx + 0.5f * q1.x * dy * dy + q0.w * dy * dx;
        if (sigma < 0.0f) continue;
        float alpha = fminf(q1.y * expf(-sigma), 0.999f);
        if (alpha < (1.0f / 255.0f)) continue;
        R += alpha * q1.z;
        G += alpha * q1.w;
        B += alpha * q2.x;
    }

    const int p = h * IMG_W + w;
    out[p]                     = fminf(fmaxf(R, 0.0f), 1.0f);
    out[IMG_H * IMG_W + p]     = fminf(fmaxf(G, 0.0f), 1.0f);
    out[2 * IMG_H * IMG_W + p] = fminf(fmaxf(B, 0.0f), 1.0f);
}

extern "C" void kernel_launch(void* const* d_in, const int* in_sizes, int n_in,
                              void* d_out, int out_size, void* d_ws, size_t ws_size,
                              hipStream_t stream) {
    const float* xyz     = (const float*)d_in[0];  // (1, N, 2)
    const float* chol    = (const float*)d_in[1];  // (1, N, 3)
    const float* opacity = (const float*)d_in[2];  // (N, 1)
    const float* fdc     = (const float*)d_in[3];  // (N, 3)
    // d_in[4] = frame_index, always 0 (T == 1)

    float4* wsp = (float4*)d_ws;                   // 2048 * 64 B = 128 KB
    float* out  = (float*)d_out;                   // (1, 3, H, W)

    prep_kernel<<<N_GAUSS / 256, 256, 0, stream>>>(xyz, chol, opacity, fdc, wsp);
    splat_tiled<<<N_TILES, 256, 0, stream>>>(wsp, out);
}

// Round 4
// 74.968 us; speedup vs baseline: 1.0622x; 1.0043x over previous
//
#include <hip/hip_runtime.h>
#include <math.h>

#define N_GAUSS 2048
#define IMG_H 512
#define IMG_W 512
#define TILE_W 64
#define TILE_H 4
#define TILES_X (IMG_W / TILE_W)    // 8
#define TILES_Y (IMG_H / TILE_H)    // 128
#define N_TILES (TILES_X * TILES_Y) // 1024

// ws layout: per gaussian, 3 x float4 (48 B):
//   q0 = (cx, cy, rx, ry)   rx < 0 => gaussian never reaches 1/255
//   q1 = (c0, c1, c2, op)
//   q2 = (cr, cg, cb, 0)

__global__ __launch_bounds__(256) void prep_kernel(
    const float* __restrict__ xyz,
    const float* __restrict__ chol,
    const float* __restrict__ opacity,
    const float* __restrict__ fdc,
    float4* __restrict__ ws)
{
    int g = blockIdx.x * 256 + threadIdx.x;
    if (g >= N_GAUSS) return;

    float mx = tanhf(xyz[2 * g]);
    float my = tanhf(xyz[2 * g + 1]);
    float cx = 0.5f * (mx + 1.0f) * (float)IMG_W;
    float cy = 0.5f * (my + 1.0f) * (float)IMG_H;

    float l1 = chol[3 * g]     + 0.5f;   // cholesky_bound = [0.5, 0, 0.5]
    float l2 = chol[3 * g + 1];
    float l3 = chol[3 * g + 2] + 0.5f;
    float s11 = l1 * l1;
    float s12 = l1 * l2;
    float s22 = l2 * l2 + l3 * l3;
    float det = s11 * s22 - s12 * s12;
    float inv = 1.0f / det;
    float c0 =  s22 * inv;
    float c1 = -s12 * inv;
    float c2 =  s11 * inv;

    float op = 1.0f / (1.0f + expf(-opacity[g]));
    float cr = 1.0f / (1.0f + expf(-fdc[3 * g]));
    float cg = 1.0f / (1.0f + expf(-fdc[3 * g + 1]));
    float cb = 1.0f / (1.0f + expf(-fdc[3 * g + 2]));

    // alpha = op*exp(-sigma) >= 1/255  =>  sigma <= log(255*op)
    float smax = logf(255.0f * op);
    float rx, ry;
    if (smax <= 0.0f) {
        rx = -1.0f; ry = -1.0f;          // never visible
    } else {
        // conservative extent from covariance diagonal (+1 px margin);
        // over-coverage is rejected by the exact per-pixel test in stage B
        rx = sqrtf(2.0f * smax * s11) + 1.0f;
        ry = sqrtf(2.0f * smax * s22) + 1.0f;
    }

    ws[g * 3 + 0] = make_float4(cx, cy, rx, ry);
    ws[g * 3 + 1] = make_float4(c0, c1, c2, op);
    ws[g * 3 + 2] = make_float4(cr, cg, cb, 0.0f);
}

__global__ __launch_bounds__(256) void splat_tiled(
    const float4* __restrict__ ws,
    float* __restrict__ out)
{
    __shared__ int s_count;
    __shared__ int s_idx[N_GAUSS];   // worst-case capacity

    const int tile = blockIdx.x;
    const int tx = tile % TILES_X;
    const int ty = tile / TILES_X;
    const int t  = threadIdx.x;

    // tile center and half-extent in pixel-center coords
    const float tcx = (float)(tx * TILE_W) + 0.5f * (float)(TILE_W - 1) + 0.5f;
    const float tcy = (float)(ty * TILE_H) + 0.5f * (float)(TILE_H - 1) + 0.5f;
    const float thw = 0.5f * (float)(TILE_W - 1);
    const float thh = 0.5f * (float)(TILE_H - 1);

    if (t == 0) s_count = 0;
    __syncthreads();

    // ---- Stage A: center/radius vs tile test, 8 gaussians per thread ----
    #pragma unroll
    for (int k = 0; k < N_GAUSS / 256; k++) {
        int g = k * 256 + t;
        float4 q0 = ws[g * 3 + 0];   // (cx, cy, rx, ry)
        if (fabsf(q0.x - tcx) <= q0.z + thw && fabsf(q0.y - tcy) <= q0.w + thh) {
            int pos = atomicAdd(&s_count, 1);
            s_idx[pos] = g;
        }
    }
    __syncthreads();

    // ---- Stage B: one thread per pixel, accumulate over survivors ----
    const int w = tx * TILE_W + (t & (TILE_W - 1));
    const int h = ty * TILE_H + (t >> 6);
    const float px = (float)w + 0.5f;
    const float py = (float)h + 0.5f;

    float R = 0.0f, G = 0.0f, B = 0.0f;
    const int cnt = s_count;
    for (int i = 0; i < cnt; i++) {
        int g = s_idx[i];
        // wave-uniform addresses -> broadcast loads, L2-hot
        float4 q0 = ws[g * 3 + 0];
        float4 q1 = ws[g * 3 + 1];
        float4 q2 = ws[g * 3 + 2];
        float dx = q0.x - px;
        float dy = q0.y - py;
        // same association order as reference
        float sigma = 0.5f * q1.x * dx * dx + 0.5f * q1.z * dy * dy + q1.y * dy * dx;
        if (sigma < 0.0f) continue;
        float alpha = fminf(q1.w * expf(-sigma), 0.999f);
        if (alpha < (1.0f / 255.0f)) continue;
        R += alpha * q2.x;
        G += alpha * q2.y;
        B += alpha * q2.z;
    }

    const int p = h * IMG_W + w;
    out[p]                     = fminf(fmaxf(R, 0.0f), 1.0f);
    out[IMG_H * IMG_W + p]     = fminf(fmaxf(G, 0.0f), 1.0f);
    out[2 * IMG_H * IMG_W + p] = fminf(fmaxf(B, 0.0f), 1.0f);
}

extern "C" void kernel_launch(void* const* d_in, const int* in_sizes, int n_in,
                              void* d_out, int out_size, void* d_ws, size_t ws_size,
                              hipStream_t stream) {
    const float* xyz     = (const float*)d_in[0];  // (1, N, 2)
    const float* chol    = (const float*)d_in[1];  // (1, N, 3)
    const float* opacity = (const float*)d_in[2];  // (N, 1)
    const float* fdc     = (const float*)d_in[3];  // (N, 3)
    // d_in[4] = frame_index, always 0 (T == 1)

    float4* wsp = (float4*)d_ws;                   // 2048 * 48 B = 96 KB
    float* out  = (float*)d_out;                   // (1, 3, H, W)

    prep_kernel<<<N_GAUSS / 256, 256, 0, stream>>>(xyz, chol, opacity, fdc, wsp);
    splat_tiled<<<N_TILES, 256, 0, stream>>>(wsp, out);
}